// Round 8
// baseline (50.500 us; speedup 1.0000x reference)
//
#include <hip/hip_runtime.h>
#include <math.h>

#define NCELL (32768 * 49)   // 1,605,632
#define NE 30
#define NC 20                // classes
#define BLK 256
#define CPB 256              // cells per block (dense-stream variant)
#define G1 6272              // 6272 * 256 == NCELL exactly (no tail)
#define F2PC 15              // float2s per cell
#define LPT 15               // dense float2 loads per thread

// partial layout per block: [resp_sum, bce_sum, sqxy_sum, sqwh_sum, nll_sum, coord_sum]

__device__ __forceinline__ void process_cell(
    const float* __restrict__ pred, const float* __restrict__ targ, int cell,
    float& a0, float& a1, float& a2, float& a3, float& a4, float& a5) {

    const float2* p2 = reinterpret_cast<const float2*>(pred + (size_t)cell * NE);
    const float2* t2 = reinterpret_cast<const float2*>(targ + (size_t)cell * NE);

    float p[30], t[12];
    #pragma unroll
    for (int i = 0; i < 15; ++i) { float2 v = p2[i]; p[2*i] = v.x; p[2*i+1] = v.y; }
    #pragma unroll
    for (int i = 0; i < 6; ++i)  { float2 v = t2[i]; t[2*i] = v.x; t[2*i+1] = v.y; }

    // 2x2 cross IoU between pred boxes (rows) and target boxes (cols)
    float iou[2][2];
    #pragma unroll
    for (int i = 0; i < 2; ++i) {
        const float pcx = p[5*i], pcy = p[5*i+1], pw = p[5*i+2], ph = p[5*i+3];
        const float alx = pcx - pw*0.5f, aly = pcy - ph*0.5f;
        const float ahx = pcx + pw*0.5f, ahy = pcy + ph*0.5f;
        const float area_a = pw * ph;
        #pragma unroll
        for (int j = 0; j < 2; ++j) {
            const float tcx = t[5*j], tcy = t[5*j+1], tw = t[5*j+2], th = t[5*j+3];
            const float blx = tcx - tw*0.5f, bly = tcy - th*0.5f;
            const float bhx = tcx + tw*0.5f, bhy = tcy + th*0.5f;
            float ix = fminf(ahx, bhx) - fmaxf(alx, blx);
            float iy = fminf(ahy, bhy) - fmaxf(aly, bly);
            ix = fmaxf(ix, 0.f); iy = fmaxf(iy, 0.f);
            const float inter = ix * iy;
            const float area_b = tw * th;
            iou[i][j] = inter / (area_a + area_b - inter + 1e-12f);
        }
    }
    // argmax over pred-box axis, first-occurrence tie break (index 0)
    const int idx0 = (iou[1][0] > iou[0][0]) ? 1 : 0;
    const int idx1 = (iou[1][1] > iou[0][1]) ? 1 : 0;

    #pragma unroll
    for (int k = 0; k < 2; ++k) {
        const bool resp = (idx0 == k || idx1 == k);
        if (resp) {
            a0 += 1.f;
            const float cp = p[5*k+4], ct = t[5*k+4];
            // logaddexp(0, cp) - cp*ct  (stable)
            a1 += fmaxf(cp, 0.f) + log1pf(expf(-fabsf(cp))) - cp * ct;
            const float dx = p[5*k]   - t[5*k];
            const float dy = p[5*k+1] - t[5*k+1];
            a2 += dx*dx + dy*dy;
            const float dw = p[5*k+2] - t[5*k+2];
            const float dh = p[5*k+3] - t[5*k+3];
            a3 += dw*dw + dh*dh;
        }
    }

    a5 += 1.f;
    // class index: clip(floor(t10), 0, 19)  (clip in float, then cast)
    const float cf = fminf(fmaxf(floorf(t[10]), 0.f), 19.f);
    const int cls = (int)cf;
    float m = p[10];
    #pragma unroll
    for (int c = 1; c < NC; ++c) m = fmaxf(m, p[10 + c]);
    float se = 0.f;
    float sel = 0.f;   // p[10+cls] via static-index select (no scratch)
    #pragma unroll
    for (int c = 0; c < NC; ++c) {
        se += expf(p[10 + c] - m);
        sel += (c == cls) ? p[10 + c] : 0.f;
    }
    a4 += -(sel - m - logf(se));
}

__global__ __launch_bounds__(BLK) void yolo_partial(
    const float* __restrict__ pred,
    const float* __restrict__ targ,
    float* __restrict__ partial) {

    const int tid  = threadIdx.x;
    const int wave = tid >> 6;
    const int lane = tid & 63;
    const int base = blockIdx.x * CPB;

    // --- dense coalesced stream of this block's target chunk ---
    // float2 j = tid + i*256, i in [0,15): 256 ≡ 1 (mod 15), so the 15
    // indices per thread hit every residue mod 15 once -> exactly one t4
    // (global float2 index ≡ 2 mod 15) per thread.
    const float2* T2 = reinterpret_cast<const float2*>(targ) + (size_t)base * F2PC;
    float2 v[LPT];
    #pragma unroll
    for (int i = 0; i < LPT; ++i) v[i] = T2[tid + i * BLK];

    const int i1 = ((2 - tid) % 15 + 15) % 15;   // which load holds the t4
    float t4 = 0.f;
    #pragma unroll
    for (int i = 0; i < LPT; ++i) t4 += (i == i1) ? v[i].x : 0.f;  // static idx, keeps loads live
    const int cloc = (tid + i1 * BLK - 2) / F2PC;  // block-local cell of this t4

    // --- ballot-compact coord cells into per-wave LDS segments ---
    __shared__ int s_idx[4][64];
    __shared__ int s_cnt[4];
    {
        const bool c = t4 > 0.f;
        const unsigned long long m = __ballot(c);
        const int pre = __popcll(m & ((1ull << lane) - 1ull));
        if (c) s_idx[wave][pre] = cloc;
        if (lane == 0) s_cnt[wave] = __popcll(m);
    }
    __syncthreads();

    const int c0 = s_cnt[0], c1 = s_cnt[1], c2 = s_cnt[2], c3 = s_cnt[3];
    const int total = c0 + c1 + c2 + c3;   // ~21 avg of 256

    float a0 = 0.f, a1 = 0.f, a2 = 0.f, a3 = 0.f, a4 = 0.f, a5 = 0.f;

    // --- dense heavy pass (single wave-pass typically); rows are L2-hot ---
    for (int i = tid; i < total; i += BLK) {
        int j = i, w = 0;
        if (j >= c0) { j -= c0; w = 1;
            if (j >= c1) { j -= c1; w = 2;
                if (j >= c2) { j -= c2; w = 3; } } }
        process_cell(pred, targ, base + s_idx[w][j], a0, a1, a2, a3, a4, a5);
    }

    // --- wave tree reduction ---
    #pragma unroll
    for (int off = 32; off > 0; off >>= 1) {
        a0 += __shfl_down(a0, off, 64);
        a1 += __shfl_down(a1, off, 64);
        a2 += __shfl_down(a2, off, 64);
        a3 += __shfl_down(a3, off, 64);
        a4 += __shfl_down(a4, off, 64);
        a5 += __shfl_down(a5, off, 64);
    }

    __shared__ float sm[4][6];
    if (lane == 0) {
        sm[wave][0] = a0; sm[wave][1] = a1; sm[wave][2] = a2;
        sm[wave][3] = a3; sm[wave][4] = a4; sm[wave][5] = a5;
    }
    __syncthreads();
    if (tid == 0) {
        #pragma unroll
        for (int k = 0; k < 6; ++k) {
            // fixed-order sum over the 4 waves -> deterministic
            float s = sm[0][k] + sm[1][k] + sm[2][k] + sm[3][k];
            partial[blockIdx.x * 6 + k] = s;
        }
    }
}

__global__ __launch_bounds__(BLK) void yolo_final(
    const float* __restrict__ partial, float* __restrict__ out) {
    __shared__ double sm[BLK][6];
    double a[6] = {0, 0, 0, 0, 0, 0};
    for (int i = threadIdx.x; i < G1; i += BLK) {
        #pragma unroll
        for (int k = 0; k < 6; ++k) a[k] += (double)partial[i * 6 + k];
    }
    #pragma unroll
    for (int k = 0; k < 6; ++k) sm[threadIdx.x][k] = a[k];
    __syncthreads();
    for (int off = BLK / 2; off > 0; off >>= 1) {
        if (threadIdx.x < off) {
            #pragma unroll
            for (int k = 0; k < 6; ++k) sm[threadIdx.x][k] += sm[threadIdx.x + off][k];
        }
        __syncthreads();
    }
    if (threadIdx.x == 0) {
        const double resp_sum  = sm[0][0];
        const double bce_sum   = sm[0][1];
        const double sqxy_sum  = sm[0][2];
        const double sqwh_sum  = sm[0][3];
        const double nll_sum   = sm[0][4];
        const double coord_sum = sm[0][5];
        const double cnt = fmax(resp_sum, 1.0);
        const double contain_loss = bce_sum / cnt;
        const double loc_loss = (sqxy_sum + sqwh_sum) / (2.0 * cnt);
        const double class_loss = nll_sum / fmax(coord_sum, 1.0);
        out[0] = (float)(class_loss + contain_loss + 5.0 * loc_loss);
    }
}

extern "C" void kernel_launch(void* const* d_in, const int* in_sizes, int n_in,
                              void* d_out, int out_size, void* d_ws, size_t ws_size,
                              hipStream_t stream) {
    const float* pred = (const float*)d_in[0];
    const float* targ = (const float*)d_in[1];
    float* partial = (float*)d_ws;   // G1*6 floats = 147 KiB

    yolo_partial<<<G1, BLK, 0, stream>>>(pred, targ, partial);
    yolo_final<<<1, BLK, 0, stream>>>(partial, (float*)d_out);
}

// Round 9
// 46.850 us; speedup vs baseline: 1.0779x; 1.0779x over previous
//
#include <hip/hip_runtime.h>
#include <math.h>

#define NCELL (32768 * 49)   // 1,605,632
#define NE 30
#define NC 20                // classes
#define BLK 256
#define CPB 784              // cells per block; 2048 * 784 == NCELL exactly
#define G1 2048              // 8 blocks/CU on 256 CUs -> one balanced round

// partial layout per block: [resp_sum, bce_sum, sqxy_sum, sqwh_sum, nll_sum, coord_sum]

__device__ __forceinline__ void process_cell(
    const float* __restrict__ pred, const float* __restrict__ targ, int cell,
    float& a0, float& a1, float& a2, float& a3, float& a4, float& a5) {

    const float2* p2 = reinterpret_cast<const float2*>(pred + (size_t)cell * NE);
    const float2* t2 = reinterpret_cast<const float2*>(targ + (size_t)cell * NE);

    float p[30], t[12];
    #pragma unroll
    for (int i = 0; i < 15; ++i) { float2 v = p2[i]; p[2*i] = v.x; p[2*i+1] = v.y; }
    #pragma unroll
    for (int i = 0; i < 6; ++i)  { float2 v = t2[i]; t[2*i] = v.x; t[2*i+1] = v.y; }

    // 2x2 cross IoU between pred boxes (rows) and target boxes (cols)
    float iou[2][2];
    #pragma unroll
    for (int i = 0; i < 2; ++i) {
        const float pcx = p[5*i], pcy = p[5*i+1], pw = p[5*i+2], ph = p[5*i+3];
        const float alx = pcx - pw*0.5f, aly = pcy - ph*0.5f;
        const float ahx = pcx + pw*0.5f, ahy = pcy + ph*0.5f;
        const float area_a = pw * ph;
        #pragma unroll
        for (int j = 0; j < 2; ++j) {
            const float tcx = t[5*j], tcy = t[5*j+1], tw = t[5*j+2], th = t[5*j+3];
            const float blx = tcx - tw*0.5f, bly = tcy - th*0.5f;
            const float bhx = tcx + tw*0.5f, bhy = tcy + th*0.5f;
            float ix = fminf(ahx, bhx) - fmaxf(alx, blx);
            float iy = fminf(ahy, bhy) - fmaxf(aly, bly);
            ix = fmaxf(ix, 0.f); iy = fmaxf(iy, 0.f);
            const float inter = ix * iy;
            const float area_b = tw * th;
            iou[i][j] = inter / (area_a + area_b - inter + 1e-12f);
        }
    }
    // argmax over pred-box axis, first-occurrence tie break (index 0)
    const int idx0 = (iou[1][0] > iou[0][0]) ? 1 : 0;
    const int idx1 = (iou[1][1] > iou[0][1]) ? 1 : 0;

    #pragma unroll
    for (int k = 0; k < 2; ++k) {
        const bool resp = (idx0 == k || idx1 == k);
        if (resp) {
            a0 += 1.f;
            const float cp = p[5*k+4], ct = t[5*k+4];
            // logaddexp(0, cp) - cp*ct  (stable)
            a1 += fmaxf(cp, 0.f) + log1pf(expf(-fabsf(cp))) - cp * ct;
            const float dx = p[5*k]   - t[5*k];
            const float dy = p[5*k+1] - t[5*k+1];
            a2 += dx*dx + dy*dy;
            const float dw = p[5*k+2] - t[5*k+2];
            const float dh = p[5*k+3] - t[5*k+3];
            a3 += dw*dw + dh*dh;
        }
    }

    a5 += 1.f;
    // class index: clip(floor(t10), 0, 19)  (clip in float, then cast)
    const float cf = fminf(fmaxf(floorf(t[10]), 0.f), 19.f);
    const int cls = (int)cf;
    float m = p[10];
    #pragma unroll
    for (int c = 1; c < NC; ++c) m = fmaxf(m, p[10 + c]);
    float se = 0.f;
    float sel = 0.f;   // p[10+cls] via static-index select (no scratch)
    #pragma unroll
    for (int c = 0; c < NC; ++c) {
        se += expf(p[10 + c] - m);
        sel += (c == cls) ? p[10 + c] : 0.f;
    }
    a4 += -(sel - m - logf(se));
}

__global__ __launch_bounds__(BLK) void yolo_partial(
    const float* __restrict__ pred,
    const float* __restrict__ targ,
    float* __restrict__ partial) {

    const int base = blockIdx.x * CPB;
    const int tid  = threadIdx.x;
    const int wave = tid >> 6;
    const int lane = tid & 63;

    // --- scan: 3 full rounds + 16-thread tail, all loads issued upfront ---
    float t4v[4];
    #pragma unroll
    for (int k = 0; k < 3; ++k)
        t4v[k] = targ[(size_t)(base + k * BLK + tid) * NE + 4];
    t4v[3] = (tid < CPB - 3 * BLK)
                 ? targ[(size_t)(base + 3 * BLK + tid) * NE + 4] : 0.f;

    // --- ballot-compact coord cells into per-wave LDS segments ---
    // (deterministic: fixed ballot -> prefix order, no atomics)
    // max cells per wave = 4 rounds (<=196 real) -> 208 slots for safety
    __shared__ int s_idx[4][208];
    __shared__ int s_cnt[4];
    int cnt = 0;
    #pragma unroll
    for (int k = 0; k < 4; ++k) {
        const bool c = t4v[k] > 0.f;
        const unsigned long long m = __ballot(c);
        const int pre = __popcll(m & ((1ull << lane) - 1ull));
        if (c) s_idx[wave][cnt + pre] = k * BLK + tid;   // block-local cell
        cnt += __popcll(m);
    }
    if (lane == 0) s_cnt[wave] = cnt;
    __syncthreads();

    const int c0 = s_cnt[0], c1 = s_cnt[1], c2 = s_cnt[2], c3 = s_cnt[3];
    const int total = c0 + c1 + c2 + c3;   // ~64 avg of 784

    float a0 = 0.f, a1 = 0.f, a2 = 0.f, a3 = 0.f, a4 = 0.f, a5 = 0.f;

    // --- dense heavy pass (typically one 256-wide iteration) ---
    for (int i = tid; i < total; i += BLK) {
        int j = i, w = 0;
        if (j >= c0) { j -= c0; w = 1;
            if (j >= c1) { j -= c1; w = 2;
                if (j >= c2) { j -= c2; w = 3; } } }
        process_cell(pred, targ, base + s_idx[w][j], a0, a1, a2, a3, a4, a5);
    }

    // --- wave tree reduction ---
    #pragma unroll
    for (int off = 32; off > 0; off >>= 1) {
        a0 += __shfl_down(a0, off, 64);
        a1 += __shfl_down(a1, off, 64);
        a2 += __shfl_down(a2, off, 64);
        a3 += __shfl_down(a3, off, 64);
        a4 += __shfl_down(a4, off, 64);
        a5 += __shfl_down(a5, off, 64);
    }

    __shared__ float sm[4][6];
    if (lane == 0) {
        sm[wave][0] = a0; sm[wave][1] = a1; sm[wave][2] = a2;
        sm[wave][3] = a3; sm[wave][4] = a4; sm[wave][5] = a5;
    }
    __syncthreads();
    if (tid == 0) {
        #pragma unroll
        for (int k = 0; k < 6; ++k) {
            // fixed-order sum over the 4 waves -> deterministic
            float s = sm[0][k] + sm[1][k] + sm[2][k] + sm[3][k];
            partial[blockIdx.x * 6 + k] = s;
        }
    }
}

__global__ __launch_bounds__(BLK) void yolo_final(
    const float* __restrict__ partial, float* __restrict__ out) {
    __shared__ double sm[BLK][6];
    double a[6] = {0, 0, 0, 0, 0, 0};
    for (int i = threadIdx.x; i < G1; i += BLK) {
        #pragma unroll
        for (int k = 0; k < 6; ++k) a[k] += (double)partial[i * 6 + k];
    }
    #pragma unroll
    for (int k = 0; k < 6; ++k) sm[threadIdx.x][k] = a[k];
    __syncthreads();
    for (int off = BLK / 2; off > 0; off >>= 1) {
        if (threadIdx.x < off) {
            #pragma unroll
            for (int k = 0; k < 6; ++k) sm[threadIdx.x][k] += sm[threadIdx.x + off][k];
        }
        __syncthreads();
    }
    if (threadIdx.x == 0) {
        const double resp_sum  = sm[0][0];
        const double bce_sum   = sm[0][1];
        const double sqxy_sum  = sm[0][2];
        const double sqwh_sum  = sm[0][3];
        const double nll_sum   = sm[0][4];
        const double coord_sum = sm[0][5];
        const double cnt = fmax(resp_sum, 1.0);
        const double contain_loss = bce_sum / cnt;
        const double loc_loss = (sqxy_sum + sqwh_sum) / (2.0 * cnt);
        const double class_loss = nll_sum / fmax(coord_sum, 1.0);
        out[0] = (float)(class_loss + contain_loss + 5.0 * loc_loss);
    }
}

extern "C" void kernel_launch(void* const* d_in, const int* in_sizes, int n_in,
                              void* d_out, int out_size, void* d_ws, size_t ws_size,
                              hipStream_t stream) {
    const float* pred = (const float*)d_in[0];
    const float* targ = (const float*)d_in[1];
    float* partial = (float*)d_ws;   // G1*6 floats = 48 KiB

    yolo_partial<<<G1, BLK, 0, stream>>>(pred, targ, partial);
    yolo_final<<<1, BLK, 0, stream>>>(partial, (float*)d_out);
}